// Round 17
// baseline (189.390 us; speedup 1.0000x reference)
//
#include <hip/hip_runtime.h>
#include <cmath>

#define Nn    8192
#define INF_  512
#define OUTF  64

typedef __attribute__((ext_vector_type(4))) int   i4;
typedef __attribute__((ext_vector_type(4))) float f4v;
typedef __attribute__((ext_vector_type(8))) short s8;
typedef __attribute__((ext_vector_type(4))) float f32x4;
typedef unsigned long long u64;

__device__ __forceinline__ float lrelu(float v) { return fmaxf(v, 0.2f * v); }

__device__ __forceinline__ unsigned int f2bf(float f) {
    unsigned int u = __float_as_uint(f);
    u = (u + 0x7FFFu + ((u >> 16) & 1u)) >> 16;
    return u;
}

// ---------------------------------------------------------------------------
// k1: Wh = x @ W -> WhT bf16 [64][N]; Wh1 = Wh@a[:64]; Wh2 = Wh@a[64:].
// DENSE x read (R15, unchanged). 1024 thr; grid N/16 = 512.
// ---------------------------------------------------------------------------
__global__ __launch_bounds__(1024, 8) void k1_wh(
    const float* __restrict__ x, const float* __restrict__ W,
    const float* __restrict__ a, unsigned short* __restrict__ WhT,
    float* __restrict__ Wh1, float* __restrict__ Wh2)
{
    __shared__ float xs[16][520];             // 33.3 KB x slab (padded)
    __shared__ float part[3][16][64];         // 12 KB k-slice partials
    __shared__ unsigned short stage[64][16];  // 2 KB bf16 transpose stage
    const int t    = threadIdx.x;
    const int row0 = blockIdx.x * 16;

    #pragma unroll
    for (int s2 = 0; s2 < 2; ++s2) {
        const int idx = s2 * 4096 + 4 * t;
        const f4v v = __builtin_nontemporal_load(
            (const f4v*)(x + (size_t)row0 * INF_ + idx));
        *(f4v*)&xs[idx >> 9][idx & 511] = v;
    }
    __syncthreads();

    const int s    = t >> 8;                  // k-slice 0..3
    const int r    = (t >> 4) & 15;           // row
    const int cg   = (t & 15) << 2;           // col group (4 cols)
    const int row  = row0 + r;
    const float* __restrict__ Wp = W + (size_t)s * 128 * OUTF;

    float4 acc = make_float4(0.f, 0.f, 0.f, 0.f);
    for (int k = 0; k < 128; k += 4) {
        const float4 xv = *(const float4*)&xs[r][s * 128 + k];
        const float* wp = Wp + (size_t)k * OUTF + cg;
        const float4 w0 = *(const float4*)(wp);
        const float4 w1 = *(const float4*)(wp + OUTF);
        const float4 w2 = *(const float4*)(wp + 2 * OUTF);
        const float4 w3 = *(const float4*)(wp + 3 * OUTF);
        acc.x += xv.x * w0.x + xv.y * w1.x + xv.z * w2.x + xv.w * w3.x;
        acc.y += xv.x * w0.y + xv.y * w1.y + xv.z * w2.y + xv.w * w3.y;
        acc.z += xv.x * w0.z + xv.y * w1.z + xv.z * w2.z + xv.w * w3.z;
        acc.w += xv.x * w0.w + xv.y * w1.w + xv.z * w2.w + xv.w * w3.w;
    }
    if (s > 0) *(float4*)&part[s - 1][r][cg] = acc;
    __syncthreads();
    if (s == 0) {
        const float4 pa = *(const float4*)&part[0][r][cg];
        const float4 pb = *(const float4*)&part[1][r][cg];
        const float4 pc = *(const float4*)&part[2][r][cg];
        acc.x += pa.x + pb.x + pc.x;
        acc.y += pa.y + pb.y + pc.y;
        acc.z += pa.z + pb.z + pc.z;
        acc.w += pa.w + pb.w + pc.w;
        stage[cg + 0][r] = (unsigned short)f2bf(acc.x);
        stage[cg + 1][r] = (unsigned short)f2bf(acc.y);
        stage[cg + 2][r] = (unsigned short)f2bf(acc.z);
        stage[cg + 3][r] = (unsigned short)f2bf(acc.w);

        float p1 = acc.x * a[cg]        + acc.y * a[cg + 1]
                 + acc.z * a[cg + 2]    + acc.w * a[cg + 3];
        float p2 = acc.x * a[OUTF + cg]     + acc.y * a[OUTF + cg + 1]
                 + acc.z * a[OUTF + cg + 2] + acc.w * a[OUTF + cg + 3];
        #pragma unroll
        for (int off = 8; off; off >>= 1) {
            p1 += __shfl_xor(p1, off);
            p2 += __shfl_xor(p2, off);
        }
        if ((t & 15) == 0) { Wh1[row] = p1; Wh2[row] = p2; }
    }
    __syncthreads();
    if (t < 256) {
        const int col = t >> 2;
        const int q   = t & 3;
        const u64 v = *(const u64*)&stage[col][q * 4];
        *(u64*)(WhT + (size_t)col * Nn + row0 + q * 4) = v;
    }
}

// ---------------------------------------------------------------------------
// k2: FUSED, 16 rows/block, 1024 thr = 16 waves, grid N/16 = 512.
//  Phase A (dense READ sweep, R15 exact): block reads its 512 KB adj slab
//    linearly, 16 KB/step -> nibbles to bm8[16][2064 padded] + per-row
//    exp-sum partials -> sm_Sp.
//  S-finish: wave w reduces row w -> sm_is[w] = 1/S; zero red[]; barrier.
//  Phase B (BARRIER-FREE, j-sliced): wave w owns js [512w, 512w+512).
//    Lane ln computes p for row (ln&15) at k-offs (ln>>4)*8+0..7 -- exactly
//    the MFMA A-frag layout -> A frags built IN REGISTERS from bm8 u16
//    nibble reads (2-way bank after pad) + Wh2 (L1) + exp. Normalized v=p*is:
//    nt att store (32B/lane, fire-and-forget) + 4 coltile MFMAs per kstep.
//    No LDS tile, no barriers; waves free-run.
//  Reduce: LDS float atomicAdd into red[4][16][16]; barrier; ELU epilogue.
// ---------------------------------------------------------------------------
__global__ __launch_bounds__(1024, 8) void k2_fused(
    const int* __restrict__ adj, const unsigned short* __restrict__ WhT,
    const float* __restrict__ Wh1, const float* __restrict__ Wh2,
    float* __restrict__ outp, float* __restrict__ att)
{
    __shared__ unsigned char bm8[16][2064];   // 33 KB masks (pad: 2-way bank)
    __shared__ float red[4][16][16];          // 4 KB cross-wave acc
    __shared__ float sm_Sp[16][16];           // 1 KB
    __shared__ float sm_is[16];

    const int t    = threadIdx.x;
    const int lane = t & 63;
    const int w    = t >> 6;
    const int row0 = blockIdx.x * 16;

    const int j0 = 4 * t;                  // this thread's j within half-row
    const f4v w4a = *(const f4v*)(Wh2 + j0);          // half 0 cols
    const f4v w4b = *(const f4v*)(Wh2 + 4096 + j0);   // half 1 cols

    // ---------------- Phase A: dense cooperative adj sweep ------------------
    {
        const i4* __restrict__ asrc = (const i4*)(adj + (size_t)row0 * Nn);
        float Sp = 0.f;
        i4 av = __builtin_nontemporal_load(asrc + t);       // step 0
        #pragma unroll
        for (int s = 0; s < 32; ++s) {
            const int r = s >> 1, h = s & 1;
            i4 nxt;
            if (s < 31)
                nxt = __builtin_nontemporal_load(asrc + (s + 1) * 1024 + t);
            const f4v w4 = h ? w4b : w4a;
            const float h1r = Wh1[row0 + r];
            const int nib = (av.x != 0 ? 1 : 0) | (av.y != 0 ? 2 : 0)
                          | (av.z != 0 ? 4 : 0) | (av.w != 0 ? 8 : 0);
            Sp += (nib & 1) ? __expf(lrelu(h1r + w4.x)) : 0.f;
            Sp += (nib & 2) ? __expf(lrelu(h1r + w4.y)) : 0.f;
            Sp += (nib & 4) ? __expf(lrelu(h1r + w4.z)) : 0.f;
            Sp += (nib & 8) ? __expf(lrelu(h1r + w4.w)) : 0.f;
            bm8[r][h * 1024 + t] = (unsigned char)nib;
            if (h) {   // row r complete for this thread: flush partial
                #pragma unroll
                for (int off = 32; off; off >>= 1) Sp += __shfl_xor(Sp, off);
                if (lane == 0) sm_Sp[r][w] = Sp;
                Sp = 0.f;
            }
            av = nxt;
        }
    }
    __syncthreads();

    // ---------------- S finish + red zero -----------------------------------
    {
        float sv = sm_Sp[w][lane & 15];
        #pragma unroll
        for (int off = 8; off; off >>= 1) sv += __shfl_xor(sv, off);
        if (lane == 0) sm_is[w] = 1.0f / sv;
    }
    ((float*)red)[t] = 0.f;
    __syncthreads();

    // ---------------- Phase B: barrier-free j-sliced MFMA + stores ----------
    const int brow = lane & 15;            // att row this lane computes
    const int kg   = lane >> 4;            // k subgroup (0..3)
    const float h1r = Wh1[row0 + brow];
    const float isr = sm_is[brow];
    const size_t rowbase = (size_t)(row0 + brow) * Nn;

    f32x4 a0 = {0.f,0.f,0.f,0.f}, a1 = {0.f,0.f,0.f,0.f};
    f32x4 a2 = {0.f,0.f,0.f,0.f}, a3 = {0.f,0.f,0.f,0.f};

    for (int ks = 0; ks < 16; ++ks) {
        const int jb = w * 512 + ks * 32 + kg * 8;
        const unsigned short nn = *(const unsigned short*)&bm8[brow][jb >> 2];
        const int nib0 = nn & 0xFF;
        const int nib1 = nn >> 8;
        const f4v wa = *(const f4v*)(Wh2 + jb);
        const f4v wb = *(const f4v*)(Wh2 + jb + 4);
        const float v0 = (nib0 & 1) ? __expf(lrelu(h1r + wa.x)) * isr : 0.f;
        const float v1 = (nib0 & 2) ? __expf(lrelu(h1r + wa.y)) * isr : 0.f;
        const float v2 = (nib0 & 4) ? __expf(lrelu(h1r + wa.z)) * isr : 0.f;
        const float v3 = (nib0 & 8) ? __expf(lrelu(h1r + wa.w)) * isr : 0.f;
        const float v4 = (nib1 & 1) ? __expf(lrelu(h1r + wb.x)) * isr : 0.f;
        const float v5 = (nib1 & 2) ? __expf(lrelu(h1r + wb.y)) * isr : 0.f;
        const float v6 = (nib1 & 4) ? __expf(lrelu(h1r + wb.z)) * isr : 0.f;
        const float v7 = (nib1 & 8) ? __expf(lrelu(h1r + wb.w)) * isr : 0.f;

        f4v sa; sa.x = v0; sa.y = v1; sa.z = v2; sa.w = v3;
        f4v sb; sb.x = v4; sb.y = v5; sb.z = v6; sb.w = v7;
        __builtin_nontemporal_store(sa, (f4v*)(att + rowbase + jb));
        __builtin_nontemporal_store(sb, (f4v*)(att + rowbase + jb + 4));

        s8 af;
        af[0] = (short)f2bf(v0); af[1] = (short)f2bf(v1);
        af[2] = (short)f2bf(v2); af[3] = (short)f2bf(v3);
        af[4] = (short)f2bf(v4); af[5] = (short)f2bf(v5);
        af[6] = (short)f2bf(v6); af[7] = (short)f2bf(v7);

        const unsigned short* __restrict__ wt = WhT + (size_t)brow * Nn + jb;
        {
            const s8 bf = *(const s8*)(wt);
            a0 = __builtin_amdgcn_mfma_f32_16x16x32_bf16(af, bf, a0, 0, 0, 0);
        }
        {
            const s8 bf = *(const s8*)(wt + (size_t)16 * Nn);
            a1 = __builtin_amdgcn_mfma_f32_16x16x32_bf16(af, bf, a1, 0, 0, 0);
        }
        {
            const s8 bf = *(const s8*)(wt + (size_t)32 * Nn);
            a2 = __builtin_amdgcn_mfma_f32_16x16x32_bf16(af, bf, a2, 0, 0, 0);
        }
        {
            const s8 bf = *(const s8*)(wt + (size_t)48 * Nn);
            a3 = __builtin_amdgcn_mfma_f32_16x16x32_bf16(af, bf, a3, 0, 0, 0);
        }
    }

    // ---------------- cross-wave reduce (LDS atomics) -----------------------
    #pragma unroll
    for (int q = 0; q < 4; ++q) {
        atomicAdd(&red[0][kg * 4 + q][brow], a0[q]);
        atomicAdd(&red[1][kg * 4 + q][brow], a1[q]);
        atomicAdd(&red[2][kg * 4 + q][brow], a2[q]);
        atomicAdd(&red[3][kg * 4 + q][brow], a3[q]);
    }
    __syncthreads();

    // ---------------- Epilogue: ELU + out store -----------------------------
    {
        const int r = t >> 6;          // 0..15
        const int c = t & 63;          // 0..63
        float v = red[c >> 4][r][c & 15];
        v = v > 0.f ? v : expm1f(v);
        outp[(size_t)(row0 + r) * OUTF + c] = v;
    }
}

// ---------------------------------------------------------------------------
extern "C" void kernel_launch(void* const* d_in, const int* in_sizes, int n_in,
                              void* d_out, int out_size, void* d_ws, size_t ws_size,
                              hipStream_t stream)
{
    const float* x   = (const float*)d_in[0];
    const int*   adj = (const int*)d_in[1];
    const float* W   = (const float*)d_in[2];
    const float* a   = (const float*)d_in[3];

    float* outp = (float*)d_out;                       // [N, 64]
    float* att  = outp + (size_t)Nn * OUTF;            // [N, N]

    // workspace: Wh1, Wh2 (f32), WhT (bf16 [64][N])  ~1.06 MB
    float* Wh1 = (float*)d_ws;
    float* Wh2 = Wh1 + Nn;
    unsigned short* WhT = (unsigned short*)(Wh2 + Nn);

    hipLaunchKernelGGL(k1_wh,    dim3(Nn / 16), dim3(1024), 0, stream,
                       x, W, a, WhT, Wh1, Wh2);
    hipLaunchKernelGGL(k2_fused, dim3(Nn / 16), dim3(1024), 0, stream,
                       adj, WhT, Wh1, Wh2, outp, att);
}

// Round 18
// 169.929 us; speedup vs baseline: 1.1145x; 1.1145x over previous
//
#include <hip/hip_runtime.h>
#include <cmath>

#define Nn    8192
#define INF_  512
#define OUTF  64

typedef __attribute__((ext_vector_type(4))) int   i4;
typedef __attribute__((ext_vector_type(4))) float f4v;
typedef __attribute__((ext_vector_type(8))) short s8;
typedef __attribute__((ext_vector_type(4))) float f32x4;
typedef unsigned long long u64;

__device__ __forceinline__ float lrelu(float v) { return fmaxf(v, 0.2f * v); }

__device__ __forceinline__ unsigned int f2bf(float f) {
    unsigned int u = __float_as_uint(f);
    u = (u + 0x7FFFu + ((u >> 16) & 1u)) >> 16;
    return u;
}

// ---------------------------------------------------------------------------
// k1: Wh = x @ W -> WhT bf16 [64][N]; Wh1/Wh2 projections; PLUS exp tables
// e1=exp(Wh1), e1q=exp(.2 Wh1), e2=exp(Wh2), e2q=exp(.2 Wh2)  (k2 needs no
// transcendentals at all). DENSE x read (R15). 1024 thr; grid N/16 = 512.
// ---------------------------------------------------------------------------
__global__ __launch_bounds__(1024, 8) void k1_wh(
    const float* __restrict__ x, const float* __restrict__ W,
    const float* __restrict__ a, unsigned short* __restrict__ WhT,
    float* __restrict__ Wh1, float* __restrict__ Wh2,
    float* __restrict__ e1g, float* __restrict__ e1qg,
    float* __restrict__ e2g, float* __restrict__ e2qg)
{
    __shared__ float xs[16][520];             // 33.3 KB x slab (padded)
    __shared__ float part[3][16][64];         // 12 KB k-slice partials
    __shared__ unsigned short stage[64][16];  // 2 KB bf16 transpose stage
    const int t    = threadIdx.x;
    const int row0 = blockIdx.x * 16;

    #pragma unroll
    for (int s2 = 0; s2 < 2; ++s2) {
        const int idx = s2 * 4096 + 4 * t;
        const f4v v = __builtin_nontemporal_load(
            (const f4v*)(x + (size_t)row0 * INF_ + idx));
        *(f4v*)&xs[idx >> 9][idx & 511] = v;
    }
    __syncthreads();

    const int s    = t >> 8;                  // k-slice 0..3
    const int r    = (t >> 4) & 15;           // row
    const int cg   = (t & 15) << 2;           // col group (4 cols)
    const int row  = row0 + r;
    const float* __restrict__ Wp = W + (size_t)s * 128 * OUTF;

    float4 acc = make_float4(0.f, 0.f, 0.f, 0.f);
    for (int k = 0; k < 128; k += 4) {
        const float4 xv = *(const float4*)&xs[r][s * 128 + k];
        const float* wp = Wp + (size_t)k * OUTF + cg;
        const float4 w0 = *(const float4*)(wp);
        const float4 w1 = *(const float4*)(wp + OUTF);
        const float4 w2 = *(const float4*)(wp + 2 * OUTF);
        const float4 w3 = *(const float4*)(wp + 3 * OUTF);
        acc.x += xv.x * w0.x + xv.y * w1.x + xv.z * w2.x + xv.w * w3.x;
        acc.y += xv.x * w0.y + xv.y * w1.y + xv.z * w2.y + xv.w * w3.y;
        acc.z += xv.x * w0.z + xv.y * w1.z + xv.z * w2.z + xv.w * w3.z;
        acc.w += xv.x * w0.w + xv.y * w1.w + xv.z * w2.w + xv.w * w3.w;
    }
    if (s > 0) *(float4*)&part[s - 1][r][cg] = acc;
    __syncthreads();
    if (s == 0) {
        const float4 pa = *(const float4*)&part[0][r][cg];
        const float4 pb = *(const float4*)&part[1][r][cg];
        const float4 pc = *(const float4*)&part[2][r][cg];
        acc.x += pa.x + pb.x + pc.x;
        acc.y += pa.y + pb.y + pc.y;
        acc.z += pa.z + pb.z + pc.z;
        acc.w += pa.w + pb.w + pc.w;
        stage[cg + 0][r] = (unsigned short)f2bf(acc.x);
        stage[cg + 1][r] = (unsigned short)f2bf(acc.y);
        stage[cg + 2][r] = (unsigned short)f2bf(acc.z);
        stage[cg + 3][r] = (unsigned short)f2bf(acc.w);

        float p1 = acc.x * a[cg]        + acc.y * a[cg + 1]
                 + acc.z * a[cg + 2]    + acc.w * a[cg + 3];
        float p2 = acc.x * a[OUTF + cg]     + acc.y * a[OUTF + cg + 1]
                 + acc.z * a[OUTF + cg + 2] + acc.w * a[OUTF + cg + 3];
        #pragma unroll
        for (int off = 8; off; off >>= 1) {
            p1 += __shfl_xor(p1, off);
            p2 += __shfl_xor(p2, off);
        }
        if ((t & 15) == 0) {
            Wh1[row] = p1;  Wh2[row] = p2;
            e1g[row]  = __expf(p1);        e1qg[row] = __expf(0.2f * p1);
            e2g[row]  = __expf(p2);        e2qg[row] = __expf(0.2f * p2);
        }
    }
    __syncthreads();
    if (t < 256) {
        const int col = t >> 2;
        const int q   = t & 3;
        const u64 v = *(const u64*)&stage[col][q * 4];
        *(u64*)(WhT + (size_t)col * Nn + row0 + q * 4) = v;
    }
}

// ---------------------------------------------------------------------------
// k2: FUSED, 16 rows/block, 1024 thr = 16 waves, grid N/16 = 512.
//  NO transcendentals anywhere (exp tables from k1).
//  Phase A (dense sweep, R15 shape): adj 16 KB/step; per element: adj bit +
//    sign bit (w2 > -h1), gated adds of e2/e2q into (pos,neg) accumulators;
//    byte = nib | (sgn<<4) -> bm8. Row flush: S = E1*pos + E1q*neg,
//    butterfly -> sm_Sp.
//  S-finish: wave w reduces row w -> sm_is[w] = 1/S.
//  Phase B (R15 lockstep, in-loop stores): per 256-j chunk: v = adjbit ?
//    (sgnbit ? E1*is*e2[j] : E1q*is*e2q[j]) : 0; f32 nt store + bf16
//    XOR-swizzled LDS tile dbuf; 2 mfma/chunk (ct=w&3, kq=w>>2), b-frag
//    prefetch; lgkmcnt(0)+s_barrier per chunk.
//  Epilogue: 4-way kq reduce, ELU, store out.
// ---------------------------------------------------------------------------
__global__ __launch_bounds__(1024, 8) void k2_fused(
    const int* __restrict__ adj, const unsigned short* __restrict__ WhT,
    const float* __restrict__ Wh1, const float* __restrict__ Wh2,
    const float* __restrict__ e1g, const float* __restrict__ e1qg,
    const float* __restrict__ e2g, const float* __restrict__ e2qg,
    float* __restrict__ outp, float* __restrict__ att)
{
    __shared__ unsigned char bm8[16][2064];   // 33 KB adj+sign bytes (padded)
    __shared__ alignas(16) unsigned short att_t[2][16 * 256];  // 16 KB
    __shared__ float red[3][4][16][16];                        // 12 KB
    __shared__ float sm_Sp[16][16];                            // 1 KB
    __shared__ float sm_is[16];

    const int t    = threadIdx.x;
    const int lane = t & 63;
    const int w    = t >> 6;               // wave id; phase B row = w
    const int row0 = blockIdx.x * 16;

    const int j0 = 4 * t;                  // this thread's j within half-row
    const f4v w4a  = *(const f4v*)(Wh2  + j0);
    const f4v w4b  = *(const f4v*)(Wh2  + 4096 + j0);
    const f4v e2a  = *(const f4v*)(e2g  + j0);
    const f4v e2b  = *(const f4v*)(e2g  + 4096 + j0);
    const f4v e2qa = *(const f4v*)(e2qg + j0);
    const f4v e2qb = *(const f4v*)(e2qg + 4096 + j0);

    // ---------------- Phase A: dense sweep, table-gated sums ----------------
    {
        const i4* __restrict__ asrc = (const i4*)(adj + (size_t)row0 * Nn);
        float Spp = 0.f, Spn = 0.f;
        i4 av = __builtin_nontemporal_load(asrc + t);       // step 0
        #pragma unroll
        for (int s = 0; s < 32; ++s) {
            const int r = s >> 1, h = s & 1;
            i4 nxt;
            if (s < 31)
                nxt = __builtin_nontemporal_load(asrc + (s + 1) * 1024 + t);
            const f4v w4  = h ? w4b  : w4a;
            const f4v ev  = h ? e2b  : e2a;
            const f4v evq = h ? e2qb : e2qa;
            const float nh1 = -Wh1[row0 + r];
            const int nib = (av.x != 0 ? 1 : 0) | (av.y != 0 ? 2 : 0)
                          | (av.z != 0 ? 4 : 0) | (av.w != 0 ? 8 : 0);
            const int sgn = (w4.x > nh1 ? 1 : 0) | (w4.y > nh1 ? 2 : 0)
                          | (w4.z > nh1 ? 4 : 0) | (w4.w > nh1 ? 8 : 0);
            Spp += ((nib & sgn) & 1) ? ev.x  : 0.f;
            Spn += ((nib & ~sgn) & 1) ? evq.x : 0.f;
            Spp += ((nib & sgn) & 2) ? ev.y  : 0.f;
            Spn += ((nib & ~sgn) & 2) ? evq.y : 0.f;
            Spp += ((nib & sgn) & 4) ? ev.z  : 0.f;
            Spn += ((nib & ~sgn) & 4) ? evq.z : 0.f;
            Spp += ((nib & sgn) & 8) ? ev.w  : 0.f;
            Spn += ((nib & ~sgn) & 8) ? evq.w : 0.f;
            bm8[r][h * 1024 + t] = (unsigned char)(nib | (sgn << 4));
            if (h) {   // row r complete: combine with row exps, flush
                float Sp = e1g[row0 + r] * Spp + e1qg[row0 + r] * Spn;
                #pragma unroll
                for (int off = 32; off; off >>= 1) Sp += __shfl_xor(Sp, off);
                if (lane == 0) sm_Sp[r][w] = Sp;
                Spp = 0.f; Spn = 0.f;
            }
            av = nxt;
        }
    }
    __syncthreads();

    // ---------------- S finish: wave w reduces row w ------------------------
    {
        float sv = sm_Sp[w][lane & 15];
        #pragma unroll
        for (int off = 8; off; off >>= 1) sv += __shfl_xor(sv, off);
        if (lane == 0) sm_is[w] = 1.0f / sv;
    }
    __syncthreads();

    const int row = row0 + w;
    const float is  = sm_is[w];
    const float E1s  = e1g[row]  * is;     // pos-branch scale
    const float E1qs = e1qg[row] * is;     // neg-branch scale

    // ---------------- Phase B: att stores + bf16 LDS + MFMA PV --------------
    const int ct = w & 3;    // col tile (16 cols)
    const int kq = w >> 2;   // k quarter (2 of 8 ksteps per chunk)
    f32x4 acc = {0.f, 0.f, 0.f, 0.f};

    auto produce = [&](int c, int bf) {
        const int jb = c * 256;
        const f4v ev  = *((const f4v*)(e2g  + jb) + lane);
        const f4v evq = *((const f4v*)(e2qg + jb) + lane);
        const int byte_ = bm8[w][c * 64 + lane];
        const int nib = byte_ & 15;
        const int sgn = byte_ >> 4;
        const float v0 = (nib & 1) ? ((sgn & 1) ? E1s * ev.x : E1qs * evq.x) : 0.f;
        const float v1 = (nib & 2) ? ((sgn & 2) ? E1s * ev.y : E1qs * evq.y) : 0.f;
        const float v2 = (nib & 4) ? ((sgn & 4) ? E1s * ev.z : E1qs * evq.z) : 0.f;
        const float v3 = (nib & 8) ? ((sgn & 8) ? E1s * ev.w : E1qs * evq.w) : 0.f;
        f4v st; st.x = v0; st.y = v1; st.z = v2; st.w = v3;
        __builtin_nontemporal_store(st, (f4v*)(att + (size_t)row * Nn + jb) + lane);
        const u64 pk = (u64)(f2bf(v0) | (f2bf(v1) << 16))
                     | ((u64)(f2bf(v2) | (f2bf(v3) << 16)) << 32);
        int byte = w * 512 + lane * 8;  byte ^= (w & 7) << 4;
        *(u64*)((char*)att_t[bf] + byte) = pk;
    };

    const int ar = lane & 15;    // MFMA A-row / B-row this lane reads
    const int ag = lane >> 4;    // k-subgroup
    auto bload = [&](int c, int ss) -> s8 {
        const int ks = kq * 2 + ss;
        return *(const s8*)(WhT + (size_t)(ct * 16 + ar) * Nn
                            + c * 256 + ks * 32 + ag * 8);
    };
    auto amfma = [&](int bf, s8 b0, s8 b1) {
        #pragma unroll
        for (int ss = 0; ss < 2; ++ss) {
            const int ks = kq * 2 + ss;
            int byte = ar * 512 + ks * 64 + ag * 16;
            byte ^= (ar & 7) << 4;
            const s8 af = *(const s8*)((char*)att_t[bf] + byte);
            acc = __builtin_amdgcn_mfma_f32_16x16x32_bf16(af, ss ? b1 : b0, acc, 0, 0, 0);
        }
    };

    s8 b0 = bload(0, 0), b1 = bload(0, 1);
    produce(0, 0);
    asm volatile("s_waitcnt lgkmcnt(0)" ::: "memory");
    __builtin_amdgcn_s_barrier();
    for (int c = 0; c < Nn / 256 - 1; ++c) {
        produce(c + 1, (c + 1) & 1);
        const s8 nb0 = bload(c + 1, 0);
        const s8 nb1 = bload(c + 1, 1);
        amfma(c & 1, b0, b1);
        asm volatile("s_waitcnt lgkmcnt(0)" ::: "memory");
        __builtin_amdgcn_s_barrier();
        b0 = nb0; b1 = nb1;
    }
    amfma((Nn / 256 - 1) & 1, b0, b1);

    // ---------------- Epilogue: kq reduce + ELU + out store -----------------
    __syncthreads();
    if (kq > 0) {
        #pragma unroll
        for (int q = 0; q < 4; ++q) red[kq - 1][ct][ag * 4 + q][ar] = acc[q];
    }
    __syncthreads();
    if (kq == 0) {
        #pragma unroll
        for (int q = 0; q < 4; ++q) {
            const int r = ag * 4 + q;
            float v = acc[q] + red[0][ct][r][ar] + red[1][ct][r][ar] + red[2][ct][r][ar];
            v = v > 0.f ? v : expm1f(v);
            outp[(size_t)(row0 + r) * OUTF + ct * 16 + ar] = v;
        }
    }
}

// ---------------------------------------------------------------------------
extern "C" void kernel_launch(void* const* d_in, const int* in_sizes, int n_in,
                              void* d_out, int out_size, void* d_ws, size_t ws_size,
                              hipStream_t stream)
{
    const float* x   = (const float*)d_in[0];
    const int*   adj = (const int*)d_in[1];
    const float* W   = (const float*)d_in[2];
    const float* a   = (const float*)d_in[3];

    float* outp = (float*)d_out;                       // [N, 64]
    float* att  = outp + (size_t)Nn * OUTF;            // [N, N]

    // workspace: Wh1, Wh2, e1, e1q, e2, e2q (f32), WhT (bf16 [64][N]) ~1.2 MB
    float* Wh1  = (float*)d_ws;
    float* Wh2  = Wh1 + Nn;
    float* e1g  = Wh2 + Nn;
    float* e1qg = e1g + Nn;
    float* e2g  = e1qg + Nn;
    float* e2qg = e2g + Nn;
    unsigned short* WhT = (unsigned short*)(e2qg + Nn);

    hipLaunchKernelGGL(k1_wh,    dim3(Nn / 16), dim3(1024), 0, stream,
                       x, W, a, WhT, Wh1, Wh2, e1g, e1qg, e2g, e2qg);
    hipLaunchKernelGGL(k2_fused, dim3(Nn / 16), dim3(1024), 0, stream,
                       adj, WhT, Wh1, Wh2, e1g, e1qg, e2g, e2qg, outp, att);
}

// Round 19
// 160.217 us; speedup vs baseline: 1.1821x; 1.0606x over previous
//
#include <hip/hip_runtime.h>
#include <cmath>

#define Nn    8192
#define INF_  512
#define OUTF  64

typedef __attribute__((ext_vector_type(4))) int   i4;
typedef __attribute__((ext_vector_type(4))) float f4v;
typedef __attribute__((ext_vector_type(8))) short s8;
typedef __attribute__((ext_vector_type(4))) float f32x4;
typedef unsigned long long u64;

__device__ __forceinline__ float lrelu(float v) { return fmaxf(v, 0.2f * v); }

__device__ __forceinline__ unsigned int f2bf(float f) {
    unsigned int u = __float_as_uint(f);
    u = (u + 0x7FFFu + ((u >> 16) & 1u)) >> 16;
    return u;
}

// ---------------------------------------------------------------------------
// k1: Wh = x @ W -> WhT bf16 [64][N]; Wh1 = Wh@a[:64]; Wh2 = Wh@a[64:].
// DENSE x read (R15 exact). 1024 thr; grid N/16 = 512.
// ---------------------------------------------------------------------------
__global__ __launch_bounds__(1024, 8) void k1_wh(
    const float* __restrict__ x, const float* __restrict__ W,
    const float* __restrict__ a, unsigned short* __restrict__ WhT,
    float* __restrict__ Wh1, float* __restrict__ Wh2)
{
    __shared__ float xs[16][520];             // 33.3 KB x slab (padded)
    __shared__ float part[3][16][64];         // 12 KB k-slice partials
    __shared__ unsigned short stage[64][16];  // 2 KB bf16 transpose stage
    const int t    = threadIdx.x;
    const int row0 = blockIdx.x * 16;

    #pragma unroll
    for (int s2 = 0; s2 < 2; ++s2) {
        const int idx = s2 * 4096 + 4 * t;
        const f4v v = __builtin_nontemporal_load(
            (const f4v*)(x + (size_t)row0 * INF_ + idx));
        *(f4v*)&xs[idx >> 9][idx & 511] = v;
    }
    __syncthreads();

    const int s    = t >> 8;                  // k-slice 0..3
    const int r    = (t >> 4) & 15;           // row
    const int cg   = (t & 15) << 2;           // col group (4 cols)
    const int row  = row0 + r;
    const float* __restrict__ Wp = W + (size_t)s * 128 * OUTF;

    float4 acc = make_float4(0.f, 0.f, 0.f, 0.f);
    for (int k = 0; k < 128; k += 4) {
        const float4 xv = *(const float4*)&xs[r][s * 128 + k];
        const float* wp = Wp + (size_t)k * OUTF + cg;
        const float4 w0 = *(const float4*)(wp);
        const float4 w1 = *(const float4*)(wp + OUTF);
        const float4 w2 = *(const float4*)(wp + 2 * OUTF);
        const float4 w3 = *(const float4*)(wp + 3 * OUTF);
        acc.x += xv.x * w0.x + xv.y * w1.x + xv.z * w2.x + xv.w * w3.x;
        acc.y += xv.x * w0.y + xv.y * w1.y + xv.z * w2.y + xv.w * w3.y;
        acc.z += xv.x * w0.z + xv.y * w1.z + xv.z * w2.z + xv.w * w3.z;
        acc.w += xv.x * w0.w + xv.y * w1.w + xv.z * w2.w + xv.w * w3.w;
    }
    if (s > 0) *(float4*)&part[s - 1][r][cg] = acc;
    __syncthreads();
    if (s == 0) {
        const float4 pa = *(const float4*)&part[0][r][cg];
        const float4 pb = *(const float4*)&part[1][r][cg];
        const float4 pc = *(const float4*)&part[2][r][cg];
        acc.x += pa.x + pb.x + pc.x;
        acc.y += pa.y + pb.y + pc.y;
        acc.z += pa.z + pb.z + pc.z;
        acc.w += pa.w + pb.w + pc.w;
        stage[cg + 0][r] = (unsigned short)f2bf(acc.x);
        stage[cg + 1][r] = (unsigned short)f2bf(acc.y);
        stage[cg + 2][r] = (unsigned short)f2bf(acc.z);
        stage[cg + 3][r] = (unsigned short)f2bf(acc.w);

        float p1 = acc.x * a[cg]        + acc.y * a[cg + 1]
                 + acc.z * a[cg + 2]    + acc.w * a[cg + 3];
        float p2 = acc.x * a[OUTF + cg]     + acc.y * a[OUTF + cg + 1]
                 + acc.z * a[OUTF + cg + 2] + acc.w * a[OUTF + cg + 3];
        #pragma unroll
        for (int off = 8; off; off >>= 1) {
            p1 += __shfl_xor(p1, off);
            p2 += __shfl_xor(p2, off);
        }
        if ((t & 15) == 0) { Wh1[row] = p1; Wh2[row] = p2; }
    }
    __syncthreads();
    if (t < 256) {
        const int col = t >> 2;
        const int q   = t & 3;
        const u64 v = *(const u64*)&stage[col][q * 4];
        *(u64*)(WhT + (size_t)col * Nn + row0 + q * 4) = v;
    }
}

// ---------------------------------------------------------------------------
// k2: FUSED, 16 rows/block, 1024 thr = 16 waves, grid N/16 = 512.
//  Phase A (dense sweep, NOW 3-DEEP pipelined — the single change vs R15):
//    block reads its 512 KB adj slab linearly, 16 KB/step, 3 steps (48 KB)
//    in flight -> nibbles to bm8[16][2048] + per-row exp-sum partials.
//  S-finish: wave w reduces row w -> sm_is[w] = 1/S.
//  Phase B (R15 exact): per 256-j chunk: att = bit ? exp(lrelu(h1+w2))*is : 0;
//    f32 nt store in-loop + bf16 XOR-swizzled LDS tile dbuf; MFMA PV
//    (ct=w&3, kq=w>>2, 2 mfma/chunk, 1-chunk b-frag prefetch);
//    lgkmcnt(0)+s_barrier per chunk.
//  Epilogue: 4-way kq reduce, ELU, store out.
// ---------------------------------------------------------------------------
__global__ __launch_bounds__(1024, 8) void k2_fused(
    const int* __restrict__ adj, const unsigned short* __restrict__ WhT,
    const float* __restrict__ Wh1, const float* __restrict__ Wh2,
    float* __restrict__ outp, float* __restrict__ att)
{
    __shared__ unsigned char bm8[16][2048];                    // 32 KB masks
    __shared__ alignas(16) unsigned short att_t[2][16 * 256];  // 16 KB
    __shared__ float red[3][4][16][16];                        // 12 KB
    __shared__ float sm_Sp[16][16];                            // 1 KB
    __shared__ float sm_is[16];

    const int t    = threadIdx.x;
    const int lane = t & 63;
    const int w    = t >> 6;               // wave id; phase B row = w
    const int row0 = blockIdx.x * 16;

    const int j0 = 4 * t;                  // this thread's j within half-row
    const f4v w4a = *(const f4v*)(Wh2 + j0);          // half 0 cols
    const f4v w4b = *(const f4v*)(Wh2 + 4096 + j0);   // half 1 cols

    // ---------------- Phase A: dense sweep, 3-deep pipeline -----------------
    {
        const i4* __restrict__ asrc = (const i4*)(adj + (size_t)row0 * Nn);
        float Sp = 0.f;
        i4 p0 = __builtin_nontemporal_load(asrc + t);
        i4 p1 = __builtin_nontemporal_load(asrc + 1024 + t);
        i4 p2 = __builtin_nontemporal_load(asrc + 2048 + t);
        #pragma unroll
        for (int s = 0; s < 32; ++s) {
            const int r = s >> 1, h = s & 1;
            const i4 av = p0;
            p0 = p1; p1 = p2;
            if (s < 29)
                p2 = __builtin_nontemporal_load(asrc + (s + 3) * 1024 + t);
            const f4v w4 = h ? w4b : w4a;
            const float h1r = Wh1[row0 + r];
            const int nib = (av.x != 0 ? 1 : 0) | (av.y != 0 ? 2 : 0)
                          | (av.z != 0 ? 4 : 0) | (av.w != 0 ? 8 : 0);
            Sp += (nib & 1) ? __expf(lrelu(h1r + w4.x)) : 0.f;
            Sp += (nib & 2) ? __expf(lrelu(h1r + w4.y)) : 0.f;
            Sp += (nib & 4) ? __expf(lrelu(h1r + w4.z)) : 0.f;
            Sp += (nib & 8) ? __expf(lrelu(h1r + w4.w)) : 0.f;
            bm8[r][h * 1024 + t] = (unsigned char)nib;
            if (h) {   // row r complete for this thread: flush partial
                #pragma unroll
                for (int off = 32; off; off >>= 1) Sp += __shfl_xor(Sp, off);
                if (lane == 0) sm_Sp[r][w] = Sp;
                Sp = 0.f;
            }
        }
    }
    __syncthreads();

    // ---------------- S finish: wave w reduces row w ------------------------
    {
        float sv = sm_Sp[w][lane & 15];
        #pragma unroll
        for (int off = 8; off; off >>= 1) sv += __shfl_xor(sv, off);
        if (lane == 0) sm_is[w] = 1.0f / sv;
    }
    __syncthreads();

    const int row = row0 + w;
    const float h1 = Wh1[row];
    const float is = sm_is[w];

    // ---------------- Phase B: att stores + bf16 LDS + MFMA PV --------------
    const int ct = w & 3;    // col tile (16 cols)
    const int kq = w >> 2;   // k quarter (2 of 8 ksteps per chunk)
    f32x4 acc = {0.f, 0.f, 0.f, 0.f};

    auto produce = [&](int c, int bf) {
        const int jb = c * 256;
        const f4v w2 = *((const f4v*)(Wh2 + jb) + lane);
        const int nib = bm8[w][c * 64 + lane];
        const float v0 = (nib & 1) ? __expf(lrelu(h1 + w2.x)) * is : 0.f;
        const float v1 = (nib & 2) ? __expf(lrelu(h1 + w2.y)) * is : 0.f;
        const float v2 = (nib & 4) ? __expf(lrelu(h1 + w2.z)) * is : 0.f;
        const float v3 = (nib & 8) ? __expf(lrelu(h1 + w2.w)) * is : 0.f;
        f4v st; st.x = v0; st.y = v1; st.z = v2; st.w = v3;
        __builtin_nontemporal_store(st, (f4v*)(att + (size_t)row * Nn + jb) + lane);
        const u64 pk = (u64)(f2bf(v0) | (f2bf(v1) << 16))
                     | ((u64)(f2bf(v2) | (f2bf(v3) << 16)) << 32);
        int byte = w * 512 + lane * 8;  byte ^= (w & 7) << 4;
        *(u64*)((char*)att_t[bf] + byte) = pk;
    };

    const int ar = lane & 15;    // MFMA A-row / B-row this lane reads
    const int ag = lane >> 4;    // k-subgroup
    auto bload = [&](int c, int ss) -> s8 {
        const int ks = kq * 2 + ss;
        return *(const s8*)(WhT + (size_t)(ct * 16 + ar) * Nn
                            + c * 256 + ks * 32 + ag * 8);
    };
    auto amfma = [&](int bf, s8 b0, s8 b1) {
        #pragma unroll
        for (int ss = 0; ss < 2; ++ss) {
            const int ks = kq * 2 + ss;
            int byte = ar * 512 + ks * 64 + ag * 16;
            byte ^= (ar & 7) << 4;
            const s8 af = *(const s8*)((char*)att_t[bf] + byte);
            acc = __builtin_amdgcn_mfma_f32_16x16x32_bf16(af, ss ? b1 : b0, acc, 0, 0, 0);
        }
    };

    s8 b0 = bload(0, 0), b1 = bload(0, 1);
    produce(0, 0);
    asm volatile("s_waitcnt lgkmcnt(0)" ::: "memory");
    __builtin_amdgcn_s_barrier();
    for (int c = 0; c < Nn / 256 - 1; ++c) {
        produce(c + 1, (c + 1) & 1);
        const s8 nb0 = bload(c + 1, 0);
        const s8 nb1 = bload(c + 1, 1);
        amfma(c & 1, b0, b1);
        asm volatile("s_waitcnt lgkmcnt(0)" ::: "memory");
        __builtin_amdgcn_s_barrier();
        b0 = nb0; b1 = nb1;
    }
    amfma((Nn / 256 - 1) & 1, b0, b1);

    // ---------------- Epilogue: kq reduce + ELU + out store -----------------
    __syncthreads();
    if (kq > 0) {
        #pragma unroll
        for (int q = 0; q < 4; ++q) red[kq - 1][ct][ag * 4 + q][ar] = acc[q];
    }
    __syncthreads();
    if (kq == 0) {
        #pragma unroll
        for (int q = 0; q < 4; ++q) {
            const int r = ag * 4 + q;
            float v = acc[q] + red[0][ct][r][ar] + red[1][ct][r][ar] + red[2][ct][r][ar];
            v = v > 0.f ? v : expm1f(v);
            outp[(size_t)(row0 + r) * OUTF + ct * 16 + ar] = v;
        }
    }
}

// ---------------------------------------------------------------------------
extern "C" void kernel_launch(void* const* d_in, const int* in_sizes, int n_in,
                              void* d_out, int out_size, void* d_ws, size_t ws_size,
                              hipStream_t stream)
{
    const float* x   = (const float*)d_in[0];
    const int*   adj = (const int*)d_in[1];
    const float* W   = (const float*)d_in[2];
    const float* a   = (const float*)d_in[3];

    float* outp = (float*)d_out;                       // [N, 64]
    float* att  = outp + (size_t)Nn * OUTF;            // [N, N]

    // workspace: Wh1, Wh2 (f32), WhT (bf16 [64][N])  ~1.06 MB
    float* Wh1 = (float*)d_ws;
    float* Wh2 = Wh1 + Nn;
    unsigned short* WhT = (unsigned short*)(Wh2 + Nn);

    hipLaunchKernelGGL(k1_wh,    dim3(Nn / 16), dim3(1024), 0, stream,
                       x, W, a, WhT, Wh1, Wh2);
    hipLaunchKernelGGL(k2_fused, dim3(Nn / 16), dim3(1024), 0, stream,
                       adj, WhT, Wh1, Wh2, outp, att);
}